// Round 2
// baseline (253.459 us; speedup 1.0000x reference)
//
#include <hip/hip_runtime.h>

// Problem constants (B,H,T,D = 4,16,4096,64; N_TASKS=8, K_LEN=128)
#define B_   4
#define H_   16
#define T_   4096
#define D_   64
#define KL_  128
#define NT_  8
#define NTOK (B_ * T_)      // 16384 tokens
#define CAP  4096           // fixed bucket capacity (avg 2048)

typedef __bf16 bf16;
typedef __attribute__((ext_vector_type(8))) __bf16 bf16x8;
typedef __attribute__((ext_vector_type(4))) __bf16 bf16x4;
typedef __attribute__((ext_vector_type(4))) float  floatx4;

// ws layout (ints): [0..7] per-task counts; [8 ..] buckets, CAP per task.

// One thread per token; wave-aggregated atomics (8 atomics/wave).
__global__ void scatter_tokens_k(const int* __restrict__ trk, int* __restrict__ ws) {
    int* counts = ws;
    int* bucket = ws + NT_;
    int idx  = blockIdx.x * blockDim.x + threadIdx.x;
    int lane = threadIdx.x & 63;
    int task = (idx < NTOK) ? trk[idx] : -1;
    unsigned long long mymask = 0ull;
    int myCnt = 0;
#pragma unroll
    for (int i = 0; i < NT_; i++) {
        unsigned long long m = __ballot(task == i);
        if (task == i) mymask = m;
        if (lane == i) myCnt = (int)__popcll(m);
    }
    int b0 = 0;
    if (lane < NT_) b0 = atomicAdd(&counts[lane], myCnt);
    int myBase = __shfl(b0, (task < 0) ? 0 : task);
    if (idx < NTOK) {
        int pos = myBase + (int)__popcll(mymask & ((1ull << lane) - 1ull));
        bucket[task * CAP + pos] = idx;
    }
}

// Per-(task, head) flash attention, S^T formulation.
// LDS: K [128][72] bf16 + V^T [64][136] bf16 = 35840 B -> 4 blocks/CU.
// No P LDS: C-layout -> A/B-layout transpose done with cross-quad shuffles.
__global__ __launch_bounds__(256, 4) void attn_k(
    const float* __restrict__ q,   const float* __restrict__ kvk,
    const float* __restrict__ kvv, const float* __restrict__ gates,
    const float* __restrict__ x,   float* __restrict__ out,
    const int* __restrict__ ws)
{
    __shared__ bf16 Kl[KL_ * 72];
    __shared__ bf16 Vt[D_ * 136];

    const int task = blockIdx.z, h = blockIdx.y, chunk = blockIdx.x;
    const int cnt = ws[task];
    if (cnt == 0) return;
    const int* bucket = ws + NT_ + task * CAP;
    const float gate = gates[task];

    // ---- stage K (row-major, stride 72) and V^T (stride 136), fp32 -> bf16 ----
    {
        const size_t kvbase = (size_t)(task * H_ + h) * (KL_ * D_ / 4);
        const float4* kf = (const float4*)kvk + kvbase;
        const float4* vf = (const float4*)kvv + kvbase;
        for (int ii = threadIdx.x; ii < KL_ * D_ / 4; ii += 256) {
            int k = ii >> 4, d4 = ii & 15;
            float4 a = kf[ii];
            bf16x4 w; w[0]=(bf16)a.x; w[1]=(bf16)a.y; w[2]=(bf16)a.z; w[3]=(bf16)a.w;
            *(bf16x4*)&Kl[k * 72 + d4 * 4] = w;
            float4 v = vf[ii];
            int d = d4 * 4;
            Vt[(d+0)*136 + k] = (bf16)v.x;
            Vt[(d+1)*136 + k] = (bf16)v.y;
            Vt[(d+2)*136 + k] = (bf16)v.z;
            Vt[(d+3)*136 + k] = (bf16)v.w;
        }
    }
    __syncthreads();

    const int wave = threadIdx.x >> 6;
    const int lane = threadIdx.x & 63;
    const int c = lane & 15, quad = lane >> 4;

    for (int ts = chunk * 4 + wave; ts * 16 < cnt; ts += 32) {
        // ---- gather Q as B-frag (n = token = lane&15, k = quad*8+j) ----
        int slot = ts * 16 + c;
        int tok  = bucket[slot < cnt ? slot : cnt - 1];
        int bb = tok >> 12, tt = tok & (T_ - 1);
        const size_t tbase = (size_t)((bb * H_ + h) * T_ + tt) * (D_ / 4);
        const float4* qf = (const float4*)q + tbase;
        bf16x8 bq[2];
#pragma unroll
        for (int dc = 0; dc < 2; dc++) {
            float4 f0 = qf[dc * 8 + quad * 2];
            float4 f1 = qf[dc * 8 + quad * 2 + 1];
            bq[dc][0]=(bf16)f0.x; bq[dc][1]=(bf16)f0.y; bq[dc][2]=(bf16)f0.z; bq[dc][3]=(bf16)f0.w;
            bq[dc][4]=(bf16)f1.x; bq[dc][5]=(bf16)f1.y; bq[dc][6]=(bf16)f1.z; bq[dc][7]=(bf16)f1.w;
        }
        // ---- S^T = K Q^T : rows = keys, cols = tokens ----
        floatx4 sc[8];
#pragma unroll
        for (int nt = 0; nt < 8; nt++) {
            floatx4 z = {0.f, 0.f, 0.f, 0.f};
            sc[nt] = z;
#pragma unroll
            for (int dc = 0; dc < 2; dc++) {
                bf16x8 ak = *(const bf16x8*)&Kl[(nt * 16 + c) * 72 + dc * 32 + quad * 8];
                sc[nt] = __builtin_amdgcn_mfma_f32_16x16x32_bf16(ak, bq[dc], sc[nt], 0, 0, 0);
            }
        }
        // ---- softmax over keys: per-lane 32 values + 2 cross-quad shuffles ----
        float m = -1e30f;
#pragma unroll
        for (int nt = 0; nt < 8; nt++)
#pragma unroll
            for (int r = 0; r < 4; r++) m = fmaxf(m, sc[nt][r]);
        m = fmaxf(m, __shfl_xor(m, 16));
        m = fmaxf(m, __shfl_xor(m, 32));
        float sum = 0.f;
        int pblo[8], pbhi[8];
#pragma unroll
        for (int nt = 0; nt < 8; nt++) {
            union { bf16x4 v; int2 i; } u;
#pragma unroll
            for (int r = 0; r < 4; r++) {
                // scale 1/sqrt(64) folded: 0.125 * log2(e)
                float p = exp2f((sc[nt][r] - m) * 0.18033688011112042f);
                sum += p;
                u.v[r] = (bf16)p;
            }
            pblo[nt] = u.i.x; pbhi[nt] = u.i.y;
        }
        sum += __shfl_xor(sum, 16);
        sum += __shfl_xor(sum, 32);

        // ---- prefetch x for epilogue (hides latency behind transpose + PV) ----
        const float4* xb = (const float4*)x + tbase;
        float4 xv[4];
#pragma unroll
        for (int dt = 0; dt < 4; dt++) xv[dt] = xb[dt * 4 + quad];

        // ---- P^T (C-layout) -> P B-frag via cross-quad shuffles, then O^T = V^T P ----
        floatx4 acc[4];
#pragma unroll
        for (int dt = 0; dt < 4; dt++) { floatx4 z = {0.f,0.f,0.f,0.f}; acc[dt] = z; }
        const int srcA = ((quad & 1) << 5) + c;   // lane of quad_s = 2*(quad&1)
        const int srcB = srcA + 16;
        const bool useB = (quad >= 2);            // nt = 2*kc + (quad>>1)
#pragma unroll
        for (int kc = 0; kc < 4; kc++) {
            int a0 = __shfl(pblo[2*kc],   srcA), b0 = __shfl(pblo[2*kc+1], srcA);
            int a1 = __shfl(pbhi[2*kc],   srcA), b1 = __shfl(pbhi[2*kc+1], srcA);
            int a2 = __shfl(pblo[2*kc],   srcB), b2 = __shfl(pblo[2*kc+1], srcB);
            int a3 = __shfl(pbhi[2*kc],   srcB), b3 = __shfl(pbhi[2*kc+1], srcB);
            union { bf16x8 v; int4 i; } pf;
            pf.i.x = useB ? b0 : a0;
            pf.i.y = useB ? b1 : a1;
            pf.i.z = useB ? b2 : a2;
            pf.i.w = useB ? b3 : a3;
#pragma unroll
            for (int dt = 0; dt < 4; dt++) {
                bf16x8 av = *(const bf16x8*)&Vt[(dt * 16 + c) * 136 + kc * 32 + quad * 8];
                acc[dt] = __builtin_amdgcn_mfma_f32_16x16x32_bf16(av, pf.v, acc[dt], 0, 0, 0);
            }
        }
        // ---- epilogue: O^T rows are d -> float4 per lane (d = dt*16+quad*4+r) ----
        if (slot < cnt) {
            float scale = gate / sum;
            float4* ob = (float4*)out + tbase;
#pragma unroll
            for (int dt = 0; dt < 4; dt++) {
                float4 o;
                o.x = xv[dt].x + acc[dt][0] * scale;
                o.y = xv[dt].y + acc[dt][1] * scale;
                o.z = xv[dt].z + acc[dt][2] * scale;
                o.w = xv[dt].w + acc[dt][3] * scale;
                ob[dt * 4 + quad] = o;
            }
        }
    }
}

extern "C" void kernel_launch(void* const* d_in, const int* in_sizes, int n_in,
                              void* d_out, int out_size, void* d_ws, size_t ws_size,
                              hipStream_t stream) {
    const float* x     = (const float*)d_in[0];
    const float* q     = (const float*)d_in[1];
    const float* kvk   = (const float*)d_in[2];
    const float* kvv   = (const float*)d_in[3];
    const float* gates = (const float*)d_in[4];
    const int*   trk   = (const int*)d_in[5];
    float* out = (float*)d_out;
    int* ws = (int*)d_ws;

    hipMemsetAsync(ws, 0, NT_ * sizeof(int), stream);
    scatter_tokens_k<<<NTOK / 256, 256, 0, stream>>>(trk, ws);
    attn_k<<<dim3(8, H_, NT_), 256, 0, stream>>>(q, kvk, kvv, gates, x, out, ws);
}